// Round 6
// baseline (484.390 us; speedup 1.0000x reference)
//
#include <hip/hip_runtime.h>
#include <hip/hip_bf16.h>
#include <math.h>

#define PI_F 3.14159265358979323846f
#define R0_F 5.0f

// ---------------------------------------------------------------------------
// ws layout:
//   P[n][816] float : per-node input projections
//     [0,48)    Pa[k*16+r]                 k=0:pa000,1:pa011,2:pa022
//     [48,240)  Pv[48+k*48+3r+i]           k=0:pv101,1:pv110,2:pv112,3:pv121
//     [240,816) Pd[240+k*144+9r+ij]        k=0:pd202,1:pd211,2:pd220,3:pd222
//   counts[N] | offs[N+1] | cursor[N] | eidx[E]   (ints, CSR by src)
// ---------------------------------------------------------------------------

static __device__ __forceinline__ float dot4(float4 a, float4 b) {
  return a.x * b.x + a.y * b.y + a.z * b.z + a.w * b.w;
}

// ------------------- K1: per-node input projections (v3: phase-split) -------
__global__ __launch_bounds__(256) void node_proj_kernel(
    const float* __restrict__ x_a, const float* __restrict__ x_v, const float* __restrict__ x_d,
    const float* __restrict__ W1_a, const float* __restrict__ W1_v, const float* __restrict__ W1_d,
    float* __restrict__ P, int N)
{
  __shared__ float S[12352];           // 48.25 KB
  const int tid = threadIdx.x;
  const int lane = tid & 63;
  const int wu = __builtin_amdgcn_readfirstlane(tid >> 6);  // uniform wave id 0..3
  const int n0 = blockIdx.x * 64;
  const int nrem = min(N - n0, 64);    // valid nodes in this block
  const int phase = blockIdx.y;

  if (phase == 0) {
    for (int idx4 = tid; idx4 < nrem * 32; idx4 += 256) {
      int n = idx4 >> 5, c4 = idx4 & 31;
      float4 v = ((const float4*)(x_a + (size_t)(n0 + n) * 128))[c4];
      float* d = &S[n * 129 + c4 * 4];
      d[0] = v.x; d[1] = v.y; d[2] = v.z; d[3] = v.w;
    }
    __syncthreads();
    float acc[12];
    #pragma unroll
    for (int q = 0; q < 12; q++) acc[q] = 0.0f;
    const float* xrow = &S[lane * 129];
    for (int c0 = 0; c0 < 128; c0 += 16) {
      float xr[16];
      #pragma unroll
      for (int j = 0; j < 16; j++) xr[j] = xrow[c0 + j];
      #pragma unroll
      for (int q = 0; q < 12; q++) {
        int o = wu * 12 + q;
        const float* wp = W1_a + (o >> 4) * 2048 + (o & 15) * 128 + c0;
        float s = 0.0f;
        #pragma unroll
        for (int j = 0; j < 16; j++) s += wp[j] * xr[j];
        acc[q] += s;
      }
    }
    __syncthreads();
    #pragma unroll
    for (int q = 0; q < 12; q++) S[lane * 49 + wu * 12 + q] = acc[q];
    __syncthreads();
    for (int u = tid; u < nrem * 12; u += 256) {
      int n = u / 12, m4 = u - n * 12;
      const float* s = &S[n * 49 + m4 * 4];
      ((float4*)(P + (size_t)(n0 + n) * 816))[m4] = make_float4(s[0], s[1], s[2], s[3]);
    }
  } else if (phase == 1) {
    for (int idx4 = tid; idx4 < nrem * 48; idx4 += 256) {
      int n = idx4 / 48, m4 = idx4 - n * 48;
      float4 v = ((const float4*)(x_v + (size_t)(n0 + n) * 192))[m4];
      float* d = &S[n * 193 + m4 * 4];
      d[0] = v.x; d[1] = v.y; d[2] = v.z; d[3] = v.w;
    }
    __syncthreads();
    float acc[16][3];
    #pragma unroll
    for (int r = 0; r < 16; r++)
      #pragma unroll
      for (int i = 0; i < 3; i++) acc[r][i] = 0.0f;
    const float* xrow = &S[lane * 193];
    for (int c0 = 0; c0 < 64; c0 += 16) {
      float xr[16][3];
      #pragma unroll
      for (int j = 0; j < 16; j++) {
        xr[j][0] = xrow[(c0 + j) * 3 + 0];
        xr[j][1] = xrow[(c0 + j) * 3 + 1];
        xr[j][2] = xrow[(c0 + j) * 3 + 2];
      }
      #pragma unroll
      for (int r = 0; r < 16; r++) {
        const float* wp = W1_v + wu * 1024 + r * 64 + c0;
        #pragma unroll
        for (int j = 0; j < 16; j++) {
          float w = wp[j];
          acc[r][0] += w * xr[j][0];
          acc[r][1] += w * xr[j][1];
          acc[r][2] += w * xr[j][2];
        }
      }
    }
    __syncthreads();
    #pragma unroll
    for (int r = 0; r < 16; r++)
      #pragma unroll
      for (int i = 0; i < 3; i++)
        S[lane * 193 + wu * 48 + r * 3 + i] = acc[r][i];
    __syncthreads();
    for (int u = tid; u < nrem * 48; u += 256) {
      int n = u / 48, m4 = u - n * 48;
      const float* s = &S[n * 193 + m4 * 4];
      ((float4*)(P + (size_t)(n0 + n) * 816 + 48))[m4] = make_float4(s[0], s[1], s[2], s[3]);
    }
  } else if (phase == 2) {
    for (int idx = tid; idx < nrem * 160; idx += 256) {
      int n = idx / 160, m = idx - n * 160, c = m / 5, ij = m - c * 5;
      S[n * 161 + m] = x_d[(size_t)(n0 + n) * 288 + c * 9 + ij];
    }
    __syncthreads();
    float acc[16][5];
    #pragma unroll
    for (int r = 0; r < 16; r++)
      #pragma unroll
      for (int t = 0; t < 5; t++) acc[r][t] = 0.0f;
    const float* xrow = &S[lane * 161];
    for (int c0 = 0; c0 < 32; c0 += 8) {
      float xr[8][5];
      #pragma unroll
      for (int j = 0; j < 8; j++)
        #pragma unroll
        for (int t = 0; t < 5; t++) xr[j][t] = xrow[(c0 + j) * 5 + t];
      #pragma unroll
      for (int r = 0; r < 16; r++) {
        const float* wp = W1_d + wu * 512 + r * 32 + c0;
        #pragma unroll
        for (int j = 0; j < 8; j++) {
          float w = wp[j];
          #pragma unroll
          for (int t = 0; t < 5; t++) acc[r][t] += w * xr[j][t];
        }
      }
    }
    #pragma unroll
    for (int h = 0; h < 2; h++) {
      __syncthreads();
      if ((lane >> 5) == h) {
        int l5 = lane & 31;
        #pragma unroll
        for (int r = 0; r < 16; r++)
          #pragma unroll
          for (int t = 0; t < 5; t++)
            S[l5 * 321 + wu * 80 + r * 5 + t] = acc[r][t];
      }
      __syncthreads();
      int nbase = h * 32;
      int cnt = min(nrem - nbase, 32);
      for (int u = tid; u < cnt * 320; u += 256) {
        int n = u / 320, m = u - n * 320;
        int kk = m / 80, mm = m - kk * 80, rr = mm / 5, t = mm - rr * 5;
        P[(size_t)(n0 + nbase + n) * 816 + 240 + kk * 144 + 9 * rr + t] = S[n * 321 + m];
      }
    }
  } else {
    for (int idx = tid; idx < nrem * 128; idx += 256) {
      int n = idx >> 7, m = idx & 127, c = m >> 2, t = m & 3;
      S[n * 129 + m] = x_d[(size_t)(n0 + n) * 288 + c * 9 + 5 + t];
    }
    __syncthreads();
    float acc[16][4];
    #pragma unroll
    for (int r = 0; r < 16; r++)
      #pragma unroll
      for (int t = 0; t < 4; t++) acc[r][t] = 0.0f;
    const float* xrow = &S[lane * 129];
    for (int c0 = 0; c0 < 32; c0 += 8) {
      float xr[8][4];
      #pragma unroll
      for (int j = 0; j < 8; j++)
        #pragma unroll
        for (int t = 0; t < 4; t++) xr[j][t] = xrow[(c0 + j) * 4 + t];
      #pragma unroll
      for (int r = 0; r < 16; r++) {
        const float* wp = W1_d + wu * 512 + r * 32 + c0;
        #pragma unroll
        for (int j = 0; j < 8; j++) {
          float w = wp[j];
          #pragma unroll
          for (int t = 0; t < 4; t++) acc[r][t] += w * xr[j][t];
        }
      }
    }
    #pragma unroll
    for (int h = 0; h < 2; h++) {
      __syncthreads();
      if ((lane >> 5) == h) {
        int l5 = lane & 31;
        #pragma unroll
        for (int r = 0; r < 16; r++)
          #pragma unroll
          for (int t = 0; t < 4; t++)
            S[l5 * 257 + wu * 64 + r * 4 + t] = acc[r][t];
      }
      __syncthreads();
      int nbase = h * 32;
      int cnt = min(nrem - nbase, 32);
      for (int u = tid; u < cnt * 256; u += 256) {
        int n = u >> 8, m = u & 255;
        int kk = m >> 6, mm = m & 63, rr = mm >> 2, t = mm & 3;
        P[(size_t)(n0 + nbase + n) * 816 + 240 + kk * 144 + 9 * rr + 5 + t] = S[n * 257 + m];
      }
    }
  }
}

// ------------------- CSR build ---------------------------------------------
__global__ void hist_kernel(const int* __restrict__ src, int* __restrict__ counts, int E) {
  int e = blockIdx.x * 256 + threadIdx.x;
  if (e < E) atomicAdd(&counts[src[e]], 1);
}

__global__ __launch_bounds__(1024) void scan_kernel(
    const int* __restrict__ counts, int* __restrict__ offs, int* __restrict__ cursor,
    int N, int E)
{
  __shared__ int part[1024];
  int tid = threadIdx.x;
  int chunk = (N + 1023) / 1024;
  int lo = tid * chunk, hi = min(lo + chunk, N);
  int s = 0;
  for (int i = lo; i < hi; i++) s += counts[i];
  part[tid] = s;
  __syncthreads();
  for (int off = 1; off < 1024; off <<= 1) {
    int v = (tid >= off) ? part[tid - off] : 0;
    __syncthreads();
    part[tid] += v;
    __syncthreads();
  }
  int run = part[tid] - s;
  for (int i = lo; i < hi; i++) { offs[i] = run; cursor[i] = run; run += counts[i]; }
  if (tid == 0) offs[N] = E;
}

__global__ void scatter_kernel(const int* __restrict__ src, int* __restrict__ cursor,
                               int* __restrict__ eidx, int E) {
  int e = blockIdx.x * 256 + threadIdx.x;
  if (e < E) { int p = atomicAdd(&cursor[src[e]], 1); eidx[p] = e; }
}

// ------------------- K2: pipelined, 4 independent waves per block ------------
// Wave-private LDS slice (2848 floats):
//   sP[2][816] @0       double-buffered gathered P[dst] (buffer = t&1)
//   q[2][176]  @1632    double-buffered radial projections
//   tab[2][16] @1984    rvtab[4] @+0..3 (rv0,rv1,rv2,1.0), outer[9] @+4..12
//   dstl[64]   @2016    int: dst | 0x80000000-if-dead
//   scal[64][12] @2080  per-edge precomp: (rv0,rv1,rv2,pad),(rad0-3),(rad4-7)
// Pipeline at iter t: read buffers[t&1] (written at t-1, ready) -> accumulate;
// stage buffers[t&1^1] for t+1 from pb regs (loads issued at t-1, latency
// covered); issue loads for t+2. rad carries the relu'd envelope so dead
// edges have q==0 and EVERY TP path is zero without a live branch; loads are
// gated by the dst sign bit only (bandwidth).
// No barriers (all LDS traffic wave-internal); no launch_bounds min-waves,
// no inline asm (both caused the rounds-2/3 scratch-demotion cliff).
#define EDGE_STEP(T, SB, QB, TB, SBN4, QBN, TBN)                               \
  {                                                                            \
    const int t_ = (T);                                                        \
    float4 sc0 = S4[520 + t_ * 3];                                             \
    float rv0 = sc0.x, rv1 = sc0.y, rv2 = sc0.z;                               \
    if (lane < 48) {                                                           \
      float v;                                                                 \
      if (ak == 0)      v = S[(SB) + ar] * S[(QB) + ar];                       \
      else if (ak == 1) v = (S[(SB) + 96 + 3 * ar] * rv0 + S[(SB) + 97 + 3 * ar] * rv1 + S[(SB) + 98 + 3 * ar] * rv2) * S[(QB) + 16 + ar]; \
      else {                                                                   \
        int b_ = (SB) + 528 + 9 * ar;                                          \
        float o = (S[b_] * rv0 + S[b_ + 3] * rv1 + S[b_ + 6] * rv2) * rv0      \
                + (S[b_ + 1] * rv0 + S[b_ + 4] * rv1 + S[b_ + 7] * rv2) * rv1  \
                + (S[b_ + 2] * rv0 + S[b_ + 5] * rv1 + S[b_ + 8] * rv2) * rv2; \
        v = o * S[(QB) + 32 + ar];                                             \
      }                                                                        \
      accA += v;                                                               \
    }                                                                          \
    _Pragma("unroll")                                                          \
    for (int p = 0; p < 12; p++) {                                             \
      float pv;                                                                \
      if (typm & (1u << p)) pv = S[(SB) + aP[p]] * rv0 + S[(SB) + aP[p] + 1] * rv1 + S[(SB) + aP[p] + 2] * rv2; \
      else                  pv = S[(SB) + aP[p]];                              \
      acc[p] += pv * S[(QB) + aQ[p]] * S[(TB) + aF[p]];                        \
    }                                                                          \
    if (t_ + 1 < cnt) {                                                        \
      if (dln >= 0) {                                                          \
        S4[(SBN4) + lane] = pb0; S4[(SBN4) + 64 + lane] = pb1;                 \
        S4[(SBN4) + 128 + lane] = pb2;                                         \
        if (lane < 12) S4[(SBN4) + 192 + lane] = pb3;                          \
      }                                                                        \
      float4 s1 = S4[520 + (t_ + 1) * 3 + 1], s2 = S4[520 + (t_ + 1) * 3 + 2]; \
      S[(QBN) + lane] = dot4(wqa[0], s1) + dot4(wqb[0], s2);                   \
      S[(QBN) + 64 + lane] = dot4(wqa[1], s1) + dot4(wqb[1], s2);              \
      if (lane < 48) S[(QBN) + 128 + lane] = dot4(wqa[2], s1) + dot4(wqb[2], s2); \
      float4 nx0 = S4[520 + (t_ + 1) * 3];                                     \
      if (lane < 13) {                                                         \
        float tv;                                                              \
        if (lane < 4) tv = (lane == 0) ? nx0.x : (lane == 1) ? nx0.y : (lane == 2) ? nx0.z : 1.0f; \
        else { int ij_ = lane - 4, i_ = ij_ / 3, j_ = ij_ - 3 * i_;            \
               float av = (i_ == 0) ? nx0.x : (i_ == 1) ? nx0.y : nx0.z;       \
               float bv = (j_ == 0) ? nx0.x : (j_ == 1) ? nx0.y : nx0.z;       \
               tv = av * bv; }                                                 \
        S[(TBN) + lane] = tv;                                                  \
      }                                                                        \
    }                                                                          \
    if (t_ + 2 < cnt) {                                                        \
      int dl2 = Si[2016 + t_ + 2];                                             \
      if (dl2 >= 0) {                                                          \
        const float4* Pp = (const float4*)(Pg + (size_t)dl2 * 816);            \
        pb0 = Pp[lane]; pb1 = Pp[64 + lane]; pb2 = Pp[128 + lane]; pb3 = Pp[l3]; \
      }                                                                        \
      dln = dl2;                                                               \
    } else dln = -1;                                                           \
  }

__global__ __launch_bounds__(256) void node_gather_kernel(
    const float* __restrict__ r_ij, const int* __restrict__ dst,
    const int* __restrict__ offs, const int* __restrict__ eidx,
    const float* __restrict__ Pg, const float* __restrict__ W2,
    const float* __restrict__ Wo_a, const float* __restrict__ Wo_v, const float* __restrict__ Wo_d,
    float* __restrict__ out, int N)
{
  __shared__ __align__(16) float Sall[11392];    // 4 x 2848 floats = 45.6 KB
  const int wid = threadIdx.x >> 6;
  const int lane = threadIdx.x & 63;
  const int n = blockIdx.x * 4 + wid;
  if (n >= N) return;
  float* S = Sall + wid * 2848;
  float4* S4 = (float4*)S;
  int* Si = (int*)S;
  const int off = offs[n], deg = offs[n + 1] - off;

  // ---- per-lane slot constants (relative offsets into sP / q / tab) ----
  int aP[12], aQ[12], aF[12];
  unsigned typm = 0;
  #pragma unroll
  for (int p = 0; p < 3; p++) {
    int t = lane + 64 * p;
    int k = t / 48, m = t - 48 * k, jj = m >> 4, r = m & 15;
    int q_ = (3 + k) * 16 + r;
    int P_, F_;
    if (k == 0)      { P_ = 16 + r;               F_ = jj; }
    else if (k == 1) { P_ = 48 + 3 * r + jj;      F_ = 3;  }
    else if (k == 2) { P_ = 192 + 3 * r;          F_ = jj; typm |= 1u << p; }
    else             { P_ = 384 + 9 * r + 3 * jj; F_ = 3;  typm |= 1u << p; }
    aP[p] = P_; aQ[p] = q_; aF[p] = F_;
  }
  #pragma unroll
  for (int p = 0; p < 9; p++) {
    int u = lane + 64 * p;
    int s = u / 144, m = u - 144 * s, ij = m >> 4, r = m & 15;
    int i = ij / 3, jj = ij - 3 * i;
    int P_, F_, q_;
    if (s == 0)      { P_ = 32 + r;              q_ = 112 + r; F_ = 4 + ij; }
    else if (s == 1) { P_ = 144 + 3 * r + i;     q_ = 128 + r; F_ = jj; }
    else if (s == 2) { P_ = 240 + 9 * r + ij;    q_ = 144 + r; F_ = 3; }
    else             { P_ = 672 + 9 * r + 3 * i; q_ = 160 + r; F_ = jj; typm |= 1u << (3 + p); }
    aP[3 + p] = P_; aQ[3 + p] = q_; aF[3 + p] = F_;
  }
  const int ak = lane >> 4, ar = lane & 15;

  // ---- hoist W2 rows ----
  float4 wqa[3], wqb[3];
  #pragma unroll
  for (int p = 0; p < 3; p++) {
    int tq = lane + 64 * p; if (tq > 175) tq = 175;
    const float4* w = (const float4*)(W2 + tq * 8);
    wqa[p] = w[0]; wqb[p] = w[1];
  }

  float accA = 0.0f, acc[12];
  #pragma unroll
  for (int p = 0; p < 12; p++) acc[p] = 0.0f;

  float4 pb0 = {}, pb1 = {}, pb2 = {}, pb3 = {};
  const int l3 = 192 + (lane < 12 ? lane : 0);
  int dln = -1;

  for (int base = 0; base < deg; base += 64) {
    const int cnt = min(deg - base, 64);
    // ---- chunk prologue: per-lane (lane=edge) scalar precompute ----
    if (lane < cnt) {
      int e = eidx[off + base + lane];
      float a = r_ij[3 * (size_t)e], b = r_ij[3 * (size_t)e + 1], c = r_ij[3 * (size_t)e + 2];
      int d = dst[e];
      float rr = a * a + b * b + c * c;
      bool live = rr < 5.0f;
      float x_sq = rr * (1.0f / R0_F);
      float env = fmaxf(1.0f - x_sq, 0.0f);     // relu'd: dead edges -> rad=0 -> q=0
      float v0 = a * (17.0f / R0_F), v1 = b * (17.0f / R0_F), v2 = c * (17.0f / R0_F);
      float nn = sqrtf(v0 * v0 + v1 * v1 + v2 * v2);
      float sig = 2.0f / (1.0f + __expf(-nn)) - 1.0f;
      float scs = sig / (nn + 1e-6f);
      float rv0 = v0 * scs, rv1 = v1 * scs, rv2 = v2 * scs;
      float c1 = __cosf(PI_F * sqrtf(x_sq));
      float two_c1 = 2.0f * c1, cm2 = 1.0f, cm1 = c1;
      float rad[8];
      rad[0] = env; rad[1] = c1 * env;
      #pragma unroll
      for (int k = 2; k < 8; k++) { float cc = two_c1 * cm1 - cm2; rad[k] = cc * env; cm2 = cm1; cm1 = cc; }
      Si[2016 + lane] = live ? d : (d | (int)0x80000000);
      S4[520 + lane * 3]     = make_float4(rv0, rv1, rv2, 0.0f);
      S4[520 + lane * 3 + 1] = make_float4(rad[0], rad[1], rad[2], rad[3]);
      S4[520 + lane * 3 + 2] = make_float4(rad[4], rad[5], rad[6], rad[7]);
    }
    // ---- warm-up: fill buffers[0] for edge 0, prefetch edge 1 ----
    {
      int d0 = Si[2016];
      if (d0 >= 0) {
        const float4* Pp = (const float4*)(Pg + (size_t)d0 * 816);
        pb0 = Pp[lane]; pb1 = Pp[64 + lane]; pb2 = Pp[128 + lane]; pb3 = Pp[l3];
      }
      float4 s1 = S4[521], s2 = S4[522];
      S[1632 + lane] = dot4(wqa[0], s1) + dot4(wqb[0], s2);
      S[1632 + 64 + lane] = dot4(wqa[1], s1) + dot4(wqb[1], s2);
      if (lane < 48) S[1632 + 128 + lane] = dot4(wqa[2], s1) + dot4(wqb[2], s2);
      float4 s0 = S4[520];
      if (lane < 13) {
        float tv;
        if (lane < 4) tv = (lane == 0) ? s0.x : (lane == 1) ? s0.y : (lane == 2) ? s0.z : 1.0f;
        else { int ij_ = lane - 4, i_ = ij_ / 3, j_ = ij_ - 3 * i_;
               float av = (i_ == 0) ? s0.x : (i_ == 1) ? s0.y : s0.z;
               float bv = (j_ == 0) ? s0.x : (j_ == 1) ? s0.y : s0.z;
               tv = av * bv; }
        S[1984 + lane] = tv;
      }
      // stage sP[0] (vmcnt wait lands here, partly hidden by the q math above)
      S4[lane] = pb0; S4[64 + lane] = pb1; S4[128 + lane] = pb2;
      if (lane < 12) S4[192 + lane] = pb3;
      dln = -1;
      if (cnt > 1) {
        int d1 = Si[2016 + 1];
        if (d1 >= 0) {
          const float4* Pp = (const float4*)(Pg + (size_t)d1 * 816);
          pb0 = Pp[lane]; pb1 = Pp[64 + lane]; pb2 = Pp[128 + lane]; pb3 = Pp[l3];
        }
        dln = d1;
      }
    }
    // ---- main pipelined loop (2x unroll makes buffer offsets compile-time) --
    for (int tt = 0; tt < cnt; tt += 2) {
      EDGE_STEP(tt, 0, 1632, 1984, 204, 1808, 2000)
      if (tt + 1 < cnt) {
        EDGE_STEP(tt + 1, 816, 1808, 2000, 0, 1632, 1984)
      }
    }
  }

  // ---------------- epilogue: rank->channel, write out ----------------
  if (lane < 48) S[lane] = accA;
  #pragma unroll
  for (int p = 0; p < 3; p++) S[48 + lane + 64 * p] = acc[p];
  #pragma unroll
  for (int p = 0; p < 9; p++) {
    int u = lane + 64 * p;
    int s = u / 144, m = u - 144 * s, ij = m >> 4, r = m & 15;
    S[240 + s * 180 + ij * 20 + r] = acc[3 + p];
  }

  const size_t baseV = (size_t)N * 128;
  const size_t baseD = (size_t)N * 320;

  // B_a
  #pragma unroll
  for (int h = 0; h < 2; h++) {
    int c = lane + 64 * h;
    float a_ = 0.0f;
    #pragma unroll
    for (int k = 0; k < 3; k++) {
      const float4* w = (const float4*)(Wo_a + k * 2048 + c * 16);
      const float4* A4 = (const float4*)(&S[k * 16]);
      #pragma unroll
      for (int cc = 0; cc < 4; cc++) a_ += dot4(w[cc], A4[cc]);
    }
    out[(size_t)n * 128 + c] = a_;
  }
  // B_v (d = lane)
  {
    float o0 = 0, o1 = 0, o2 = 0;
    #pragma unroll
    for (int k = 0; k < 4; k++) {
      const float4* w = (const float4*)(Wo_v + k * 1024 + lane * 16);
      float4 w0 = w[0], w1 = w[1], w2 = w[2], w3 = w[3];
      #pragma unroll
      for (int j = 0; j < 3; j++) {
        const float4* A4 = (const float4*)(&S[48 + k * 48 + j * 16]);
        float v = dot4(w0, A4[0]) + dot4(w1, A4[1]) + dot4(w2, A4[2]) + dot4(w3, A4[3]);
        if (j == 0) o0 += v; else if (j == 1) o1 += v; else o2 += v;
      }
    }
    size_t ov = baseV + (size_t)n * 192 + lane * 3;
    out[ov] = o0; out[ov + 1] = o1; out[ov + 2] = o2;
  }
  // B_d
  #pragma unroll
  for (int p = 0; p < 5; p++) {
    int t = lane + 64 * p;
    if (t < 288) {
      int d = t / 9, ij = t - 9 * d;
      float a_ = 0.0f;
      #pragma unroll
      for (int s = 0; s < 4; s++) {
        const float4* w = (const float4*)(Wo_d + s * 512 + d * 16);
        const float4* A4 = (const float4*)(&S[240 + s * 180 + ij * 20]);
        a_ += dot4(w[0], A4[0]) + dot4(w[1], A4[1]) + dot4(w[2], A4[2]) + dot4(w[3], A4[3]);
      }
      out[baseD + (size_t)n * 288 + t] = a_;
    }
  }
}

// ---------------------------------------------------------------------------
extern "C" void kernel_launch(void* const* d_in, const int* in_sizes, int n_in,
                              void* d_out, int out_size, void* d_ws, size_t ws_size,
                              hipStream_t stream) {
  const float* r_ij = (const float*)d_in[0];
  const float* x_a  = (const float*)d_in[1];
  const float* x_v  = (const float*)d_in[2];
  const float* x_d  = (const float*)d_in[3];
  const float* W1_a = (const float*)d_in[4];
  const float* W1_v = (const float*)d_in[5];
  const float* W1_d = (const float*)d_in[6];
  const float* W2   = (const float*)d_in[7];
  const float* Wo_a = (const float*)d_in[8];
  const float* Wo_v = (const float*)d_in[9];
  const float* Wo_d = (const float*)d_in[10];
  const int*  src   = (const int*)d_in[11];
  const int*  dst   = (const int*)d_in[12];

  const int E = in_sizes[0] / 3;
  const int N = in_sizes[1] / 128;

  float* P    = (float*)d_ws;
  int* counts = (int*)(P + (size_t)N * 816);
  int* offs   = counts + N;
  int* cursor = offs + N + 1;
  int* eidx   = cursor + N;

  hipMemsetAsync(counts, 0, sizeof(int) * (size_t)N, stream);

  hist_kernel<<<(E + 255) / 256, 256, 0, stream>>>(src, counts, E);
  scan_kernel<<<1, 1024, 0, stream>>>(counts, offs, cursor, N, E);
  scatter_kernel<<<(E + 255) / 256, 256, 0, stream>>>(src, cursor, eidx, E);
  dim3 g1((N + 63) / 64, 4);
  node_proj_kernel<<<g1, 256, 0, stream>>>(x_a, x_v, x_d, W1_a, W1_v, W1_d, P, N);
  node_gather_kernel<<<(N + 3) / 4, 256, 0, stream>>>(r_ij, dst, offs, eidx, P, W2,
                                                      Wo_a, Wo_v, Wo_d, (float*)d_out, N);
}

// Round 7
// 456.718 us; speedup vs baseline: 1.0606x; 1.0606x over previous
//
#include <hip/hip_runtime.h>
#include <hip/hip_bf16.h>
#include <math.h>

#define PI_F 3.14159265358979323846f
#define R0_F 5.0f

// ---------------------------------------------------------------------------
// ws layout:
//   P[n][816] float : per-node input projections
//     [0,48)    Pa[k*16+r]                 k=0:pa000,1:pa011,2:pa022
//     [48,240)  Pv[48+k*48+3r+i]           k=0:pv101,1:pv110,2:pv112,3:pv121
//     [240,816) Pd[240+k*144+9r+ij]        k=0:pd202,1:pd211,2:pd220,3:pd222
//   counts[N] | offs[N+1] | cursor[N] | eidx[E]   (ints, CSR by src)
// ---------------------------------------------------------------------------

static __device__ __forceinline__ float dot4(float4 a, float4 b) {
  return a.x * b.x + a.y * b.y + a.z * b.z + a.w * b.w;
}

// ------------------- K1: per-node input projections (v3: phase-split) -------
__global__ __launch_bounds__(256) void node_proj_kernel(
    const float* __restrict__ x_a, const float* __restrict__ x_v, const float* __restrict__ x_d,
    const float* __restrict__ W1_a, const float* __restrict__ W1_v, const float* __restrict__ W1_d,
    float* __restrict__ P, int N)
{
  __shared__ float S[12352];           // 48.25 KB
  const int tid = threadIdx.x;
  const int lane = tid & 63;
  const int wu = __builtin_amdgcn_readfirstlane(tid >> 6);  // uniform wave id 0..3
  const int n0 = blockIdx.x * 64;
  const int nrem = min(N - n0, 64);    // valid nodes in this block
  const int phase = blockIdx.y;

  if (phase == 0) {
    for (int idx4 = tid; idx4 < nrem * 32; idx4 += 256) {
      int n = idx4 >> 5, c4 = idx4 & 31;
      float4 v = ((const float4*)(x_a + (size_t)(n0 + n) * 128))[c4];
      float* d = &S[n * 129 + c4 * 4];
      d[0] = v.x; d[1] = v.y; d[2] = v.z; d[3] = v.w;
    }
    __syncthreads();
    float acc[12];
    #pragma unroll
    for (int q = 0; q < 12; q++) acc[q] = 0.0f;
    const float* xrow = &S[lane * 129];
    for (int c0 = 0; c0 < 128; c0 += 16) {
      float xr[16];
      #pragma unroll
      for (int j = 0; j < 16; j++) xr[j] = xrow[c0 + j];
      #pragma unroll
      for (int q = 0; q < 12; q++) {
        int o = wu * 12 + q;
        const float* wp = W1_a + (o >> 4) * 2048 + (o & 15) * 128 + c0;
        float s = 0.0f;
        #pragma unroll
        for (int j = 0; j < 16; j++) s += wp[j] * xr[j];
        acc[q] += s;
      }
    }
    __syncthreads();
    #pragma unroll
    for (int q = 0; q < 12; q++) S[lane * 49 + wu * 12 + q] = acc[q];
    __syncthreads();
    for (int u = tid; u < nrem * 12; u += 256) {
      int n = u / 12, m4 = u - n * 12;
      const float* s = &S[n * 49 + m4 * 4];
      ((float4*)(P + (size_t)(n0 + n) * 816))[m4] = make_float4(s[0], s[1], s[2], s[3]);
    }
  } else if (phase == 1) {
    for (int idx4 = tid; idx4 < nrem * 48; idx4 += 256) {
      int n = idx4 / 48, m4 = idx4 - n * 48;
      float4 v = ((const float4*)(x_v + (size_t)(n0 + n) * 192))[m4];
      float* d = &S[n * 193 + m4 * 4];
      d[0] = v.x; d[1] = v.y; d[2] = v.z; d[3] = v.w;
    }
    __syncthreads();
    float acc[16][3];
    #pragma unroll
    for (int r = 0; r < 16; r++)
      #pragma unroll
      for (int i = 0; i < 3; i++) acc[r][i] = 0.0f;
    const float* xrow = &S[lane * 193];
    for (int c0 = 0; c0 < 64; c0 += 16) {
      float xr[16][3];
      #pragma unroll
      for (int j = 0; j < 16; j++) {
        xr[j][0] = xrow[(c0 + j) * 3 + 0];
        xr[j][1] = xrow[(c0 + j) * 3 + 1];
        xr[j][2] = xrow[(c0 + j) * 3 + 2];
      }
      #pragma unroll
      for (int r = 0; r < 16; r++) {
        const float* wp = W1_v + wu * 1024 + r * 64 + c0;
        #pragma unroll
        for (int j = 0; j < 16; j++) {
          float w = wp[j];
          acc[r][0] += w * xr[j][0];
          acc[r][1] += w * xr[j][1];
          acc[r][2] += w * xr[j][2];
        }
      }
    }
    __syncthreads();
    #pragma unroll
    for (int r = 0; r < 16; r++)
      #pragma unroll
      for (int i = 0; i < 3; i++)
        S[lane * 193 + wu * 48 + r * 3 + i] = acc[r][i];
    __syncthreads();
    for (int u = tid; u < nrem * 48; u += 256) {
      int n = u / 48, m4 = u - n * 48;
      const float* s = &S[n * 193 + m4 * 4];
      ((float4*)(P + (size_t)(n0 + n) * 816 + 48))[m4] = make_float4(s[0], s[1], s[2], s[3]);
    }
  } else if (phase == 2) {
    for (int idx = tid; idx < nrem * 160; idx += 256) {
      int n = idx / 160, m = idx - n * 160, c = m / 5, ij = m - c * 5;
      S[n * 161 + m] = x_d[(size_t)(n0 + n) * 288 + c * 9 + ij];
    }
    __syncthreads();
    float acc[16][5];
    #pragma unroll
    for (int r = 0; r < 16; r++)
      #pragma unroll
      for (int t = 0; t < 5; t++) acc[r][t] = 0.0f;
    const float* xrow = &S[lane * 161];
    for (int c0 = 0; c0 < 32; c0 += 8) {
      float xr[8][5];
      #pragma unroll
      for (int j = 0; j < 8; j++)
        #pragma unroll
        for (int t = 0; t < 5; t++) xr[j][t] = xrow[(c0 + j) * 5 + t];
      #pragma unroll
      for (int r = 0; r < 16; r++) {
        const float* wp = W1_d + wu * 512 + r * 32 + c0;
        #pragma unroll
        for (int j = 0; j < 8; j++) {
          float w = wp[j];
          #pragma unroll
          for (int t = 0; t < 5; t++) acc[r][t] += w * xr[j][t];
        }
      }
    }
    #pragma unroll
    for (int h = 0; h < 2; h++) {
      __syncthreads();
      if ((lane >> 5) == h) {
        int l5 = lane & 31;
        #pragma unroll
        for (int r = 0; r < 16; r++)
          #pragma unroll
          for (int t = 0; t < 5; t++)
            S[l5 * 321 + wu * 80 + r * 5 + t] = acc[r][t];
      }
      __syncthreads();
      int nbase = h * 32;
      int cnt = min(nrem - nbase, 32);
      for (int u = tid; u < cnt * 320; u += 256) {
        int n = u / 320, m = u - n * 320;
        int kk = m / 80, mm = m - kk * 80, rr = mm / 5, t = mm - rr * 5;
        P[(size_t)(n0 + nbase + n) * 816 + 240 + kk * 144 + 9 * rr + t] = S[n * 321 + m];
      }
    }
  } else {
    for (int idx = tid; idx < nrem * 128; idx += 256) {
      int n = idx >> 7, m = idx & 127, c = m >> 2, t = m & 3;
      S[n * 129 + m] = x_d[(size_t)(n0 + n) * 288 + c * 9 + 5 + t];
    }
    __syncthreads();
    float acc[16][4];
    #pragma unroll
    for (int r = 0; r < 16; r++)
      #pragma unroll
      for (int t = 0; t < 4; t++) acc[r][t] = 0.0f;
    const float* xrow = &S[lane * 129];
    for (int c0 = 0; c0 < 32; c0 += 8) {
      float xr[8][4];
      #pragma unroll
      for (int j = 0; j < 8; j++)
        #pragma unroll
        for (int t = 0; t < 4; t++) xr[j][t] = xrow[(c0 + j) * 4 + t];
      #pragma unroll
      for (int r = 0; r < 16; r++) {
        const float* wp = W1_d + wu * 512 + r * 32 + c0;
        #pragma unroll
        for (int j = 0; j < 8; j++) {
          float w = wp[j];
          #pragma unroll
          for (int t = 0; t < 4; t++) acc[r][t] += w * xr[j][t];
        }
      }
    }
    #pragma unroll
    for (int h = 0; h < 2; h++) {
      __syncthreads();
      if ((lane >> 5) == h) {
        int l5 = lane & 31;
        #pragma unroll
        for (int r = 0; r < 16; r++)
          #pragma unroll
          for (int t = 0; t < 4; t++)
            S[l5 * 257 + wu * 64 + r * 4 + t] = acc[r][t];
      }
      __syncthreads();
      int nbase = h * 32;
      int cnt = min(nrem - nbase, 32);
      for (int u = tid; u < cnt * 256; u += 256) {
        int n = u >> 8, m = u & 255;
        int kk = m >> 6, mm = m & 63, rr = mm >> 2, t = mm & 3;
        P[(size_t)(n0 + nbase + n) * 816 + 240 + kk * 144 + 9 * rr + 5 + t] = S[n * 257 + m];
      }
    }
  }
}

// ------------------- CSR build ---------------------------------------------
__global__ void hist_kernel(const int* __restrict__ src, int* __restrict__ counts, int E) {
  int e = blockIdx.x * 256 + threadIdx.x;
  if (e < E) atomicAdd(&counts[src[e]], 1);
}

__global__ __launch_bounds__(1024) void scan_kernel(
    const int* __restrict__ counts, int* __restrict__ offs, int* __restrict__ cursor,
    int N, int E)
{
  __shared__ int part[1024];
  int tid = threadIdx.x;
  int chunk = (N + 1023) / 1024;
  int lo = tid * chunk, hi = min(lo + chunk, N);
  int s = 0;
  for (int i = lo; i < hi; i++) s += counts[i];
  part[tid] = s;
  __syncthreads();
  for (int off = 1; off < 1024; off <<= 1) {
    int v = (tid >= off) ? part[tid - off] : 0;
    __syncthreads();
    part[tid] += v;
    __syncthreads();
  }
  int run = part[tid] - s;
  for (int i = lo; i < hi; i++) { offs[i] = run; cursor[i] = run; run += counts[i]; }
  if (tid == 0) offs[N] = E;
}

__global__ void scatter_kernel(const int* __restrict__ src, int* __restrict__ cursor,
                               int* __restrict__ eidx, int E) {
  int e = blockIdx.x * 256 + threadIdx.x;
  if (e < E) { int p = atomicAdd(&cursor[src[e]], 1); eidx[p] = e; }
}

// ------------------- K2 v7: compacted + single-buffer pipelined --------------
// 4 independent waves per 256-thread block, one node each, wave-private LDS
// slice of 1872 floats. NO barriers (all LDS traffic wave-internal, in-order
// per wave). Chunk prologue (lane = edge): ballot-compact live edges (rr<5),
// precompute rv/rad per live edge into scal[]. Main loop per edge t:
//   read sP/q/tab (staged at t-1 -> zero turnaround) -> accumulate;
//   stage t+1's sP/q/tab (pb regs loaded at t-1; DS in-order per wave makes
//   single-buffer write-after-read-issue safe);
//   issue P-row loads for t+2 (one full iteration of VMEM latency cover).
// No inline asm, no launch_bounds min-waves (rounds-2/3 scratch cliff).
// Per-wave LDS float map (1872):
//   [0,816)     sP       gathered P[dst] for current edge
//   [816,992)   q        176 radial projections (i*16+r)
//   [992,1008)  tab      rv0,rv1,rv2,1.0 @992; outer[ij] @996..1004
//   [1008,1072) dstl     int dst per compacted edge
//   [1072,1840) scal     per-edge float4 x3: (rv0,rv1,rv2,0),(rad0-3),(rad4-7)
// Epilogue reuses [0,960) as ACC (same as before).
__global__ __launch_bounds__(256) void node_gather_kernel(
    const float* __restrict__ r_ij, const int* __restrict__ dst,
    const int* __restrict__ offs, const int* __restrict__ eidx,
    const float* __restrict__ Pg, const float* __restrict__ W2,
    const float* __restrict__ Wo_a, const float* __restrict__ Wo_v, const float* __restrict__ Wo_d,
    float* __restrict__ out, int N)
{
  __shared__ __align__(16) float Sall[7488];    // 4 x 1872 = 29.95 KB
  const int wid = threadIdx.x >> 6;
  const int lane = threadIdx.x & 63;
  const int n = blockIdx.x * 4 + wid;
  if (n >= N) return;
  float* S = Sall + wid * 1872;
  float4* S4 = (float4*)S;
  int* Si = (int*)S;
  const int off = offs[n], deg = offs[n + 1] - off;

  // ---- per-lane slot constants (V slots p=0..2, D slots p=3..11) ----
  int aP[12], aQ[12], aF[12];
  unsigned typm = 0;  // bit p set => dot3-with-rv form
  #pragma unroll
  for (int p = 0; p < 3; p++) {
    int t = lane + 64 * p;                 // < 192 always
    int k = t / 48, m = t - 48 * k, jj = m >> 4, r = m & 15;
    int q_ = 816 + (3 + k) * 16 + r;       // q3..q6
    int P_, F_;
    if (k == 0)      { P_ = 16 + r;              F_ = 992 + jj; }
    else if (k == 1) { P_ = 48 + 3 * r + jj;     F_ = 995; }
    else if (k == 2) { P_ = 192 + 3 * r;         F_ = 992 + jj; typm |= 1u << p; }
    else             { P_ = 384 + 9 * r + 3 * jj; F_ = 995;     typm |= 1u << p; }
    aP[p] = P_; aQ[p] = q_; aF[p] = F_;
  }
  #pragma unroll
  for (int p = 0; p < 9; p++) {
    int u = lane + 64 * p;                 // < 576 always
    int s = u / 144, m = u - 144 * s, ij = m >> 4, r = m & 15;
    int i = ij / 3, jj = ij - 3 * i;
    int P_, F_, q_;
    if (s == 0)      { P_ = 32 + r;              q_ = 112 + r; F_ = 996 + ij; }
    else if (s == 1) { P_ = 144 + 3 * r + i;     q_ = 128 + r; F_ = 992 + jj; }
    else if (s == 2) { P_ = 240 + 9 * r + ij;    q_ = 144 + r; F_ = 995; }
    else             { P_ = 672 + 9 * r + 3 * i; q_ = 160 + r; F_ = 992 + jj; typm |= 1u << (3 + p); }
    aP[3 + p] = P_; aQ[3 + p] = 816 + q_; aF[3 + p] = F_;
  }
  const int ak = lane >> 4, ar = lane & 15;   // A slot (lane<48)

  // ---- hoist W2 rows for this lane's q slots ----
  float4 wqa[3], wqb[3];
  #pragma unroll
  for (int p = 0; p < 3; p++) {
    int tq = lane + 64 * p; if (tq > 175) tq = 175;
    const float4* w = (const float4*)(W2 + tq * 8);
    wqa[p] = w[0]; wqb[p] = w[1];
  }

  float accA = 0.0f, acc[12];
  #pragma unroll
  for (int p = 0; p < 12; p++) acc[p] = 0.0f;

  float4 pb0 = {}, pb1 = {}, pb2 = {}, pb3 = {};
  const int l3 = 192 + (lane < 12 ? lane : 0);

  for (int base = 0; base < deg; base += 64) {
    const int cnt = min(deg - base, 64);
    // ---- chunk prologue: lane = edge; compute + ballot-compact live edges --
    bool live = false;
    float a = 0, b = 0, c = 0;
    int d = 0;
    if (lane < cnt) {
      int e = eidx[off + base + lane];
      a = r_ij[3 * (size_t)e]; b = r_ij[3 * (size_t)e + 1]; c = r_ij[3 * (size_t)e + 2];
      d = dst[e];
      live = (a * a + b * b + c * c) < 5.0f;
    }
    unsigned long long mb = __ballot(live);
    const int cl = __popcll(mb);          // live count (wave-uniform)
    if (live) {
      int pos = __popcll(mb & ((1ull << lane) - 1ull));
      float rr = a * a + b * b + c * c;
      float x_sq = rr * (1.0f / R0_F);
      float env = 1.0f - x_sq;            // > 0 for live edges
      float v0 = a * (17.0f / R0_F), v1 = b * (17.0f / R0_F), v2 = c * (17.0f / R0_F);
      float nn = sqrtf(v0 * v0 + v1 * v1 + v2 * v2);
      float sig = 2.0f / (1.0f + __expf(-nn)) - 1.0f;
      float scs = sig / (nn + 1e-6f);
      float rv0 = v0 * scs, rv1 = v1 * scs, rv2 = v2 * scs;
      float c1 = __cosf(PI_F * sqrtf(x_sq));
      float two_c1 = 2.0f * c1, cm2 = 1.0f, cm1 = c1;
      float rad[8];
      rad[0] = env; rad[1] = c1 * env;
      #pragma unroll
      for (int k = 2; k < 8; k++) { float cc = two_c1 * cm1 - cm2; rad[k] = cc * env; cm2 = cm1; cm1 = cc; }
      Si[1008 + pos] = d;
      S4[268 + 3 * pos]     = make_float4(rv0, rv1, rv2, 0.0f);
      S4[268 + 3 * pos + 1] = make_float4(rad[0], rad[1], rad[2], rad[3]);
      S4[268 + 3 * pos + 2] = make_float4(rad[4], rad[5], rad[6], rad[7]);
    }
    if (cl == 0) continue;
    // ---- warm-up: stage edge 0, prefetch edge 1 ----
    {
      int d0 = Si[1008];
      const float4* Pp = (const float4*)(Pg + (size_t)d0 * 816);
      pb0 = Pp[lane]; pb1 = Pp[64 + lane]; pb2 = Pp[128 + lane]; pb3 = Pp[l3];
      S4[lane] = pb0; S4[64 + lane] = pb1; S4[128 + lane] = pb2;
      if (lane < 12) S4[192 + lane] = pb3;
      float4 s1 = S4[269], s2 = S4[270];
      S[816 + lane] = dot4(wqa[0], s1) + dot4(wqb[0], s2);
      S[880 + lane] = dot4(wqa[1], s1) + dot4(wqb[1], s2);
      if (lane < 48) S[944 + lane] = dot4(wqa[2], s1) + dot4(wqb[2], s2);
      float4 s0 = S4[268];
      if (lane < 13) {
        float tv;
        if (lane < 4) tv = (lane == 0) ? s0.x : (lane == 1) ? s0.y : (lane == 2) ? s0.z : 1.0f;
        else { int ij_ = lane - 4, i_ = ij_ / 3, j_ = ij_ - 3 * i_;
               float av = (i_ == 0) ? s0.x : (i_ == 1) ? s0.y : s0.z;
               float bv = (j_ == 0) ? s0.x : (j_ == 1) ? s0.y : s0.z;
               tv = av * bv; }
        S[992 + lane] = tv;
      }
      if (cl > 1) {
        int d1 = Si[1009];
        const float4* Pq = (const float4*)(Pg + (size_t)d1 * 816);
        pb0 = Pq[lane]; pb1 = Pq[64 + lane]; pb2 = Pq[128 + lane]; pb3 = Pq[l3];
      }
    }
    // ---- main loop: all edges live, buffers staged one iteration ahead ----
    for (int t = 0; t < cl; t++) {
      float4 sc0 = S4[268 + 3 * t];
      float rv0 = sc0.x, rv1 = sc0.y, rv2 = sc0.z;
      // A slot
      if (lane < 48) {
        float v;
        if (ak == 0)      v = S[ar] * S[816 + ar];
        else if (ak == 1) v = (S[96 + 3 * ar] * rv0 + S[97 + 3 * ar] * rv1 + S[98 + 3 * ar] * rv2) * S[832 + ar];
        else {
          int bb = 528 + 9 * ar;
          float o = (S[bb] * rv0 + S[bb + 3] * rv1 + S[bb + 6] * rv2) * rv0
                  + (S[bb + 1] * rv0 + S[bb + 4] * rv1 + S[bb + 7] * rv2) * rv1
                  + (S[bb + 2] * rv0 + S[bb + 5] * rv1 + S[bb + 8] * rv2) * rv2;
          v = o * S[848 + ar];
        }
        accA += v;
      }
      // V + D slots, unified form
      #pragma unroll
      for (int p = 0; p < 12; p++) {
        float pv;
        if (typm & (1u << p)) pv = S[aP[p]] * rv0 + S[aP[p] + 1] * rv1 + S[aP[p] + 2] * rv2;
        else                  pv = S[aP[p]];
        acc[p] += pv * S[aQ[p]] * S[aF[p]];
      }
      // stage t+1 (single buffer: DS in-order per wave, reads above already
      // issued -> safe to overwrite)
      if (t + 1 < cl) {
        S4[lane] = pb0; S4[64 + lane] = pb1; S4[128 + lane] = pb2;
        if (lane < 12) S4[192 + lane] = pb3;
        float4 s1 = S4[268 + 3 * (t + 1) + 1], s2 = S4[268 + 3 * (t + 1) + 2];
        S[816 + lane] = dot4(wqa[0], s1) + dot4(wqb[0], s2);
        S[880 + lane] = dot4(wqa[1], s1) + dot4(wqb[1], s2);
        if (lane < 48) S[944 + lane] = dot4(wqa[2], s1) + dot4(wqb[2], s2);
        float4 nx0 = S4[268 + 3 * (t + 1)];
        if (lane < 13) {
          float tv;
          if (lane < 4) tv = (lane == 0) ? nx0.x : (lane == 1) ? nx0.y : (lane == 2) ? nx0.z : 1.0f;
          else { int ij_ = lane - 4, i_ = ij_ / 3, j_ = ij_ - 3 * i_;
                 float av = (i_ == 0) ? nx0.x : (i_ == 1) ? nx0.y : nx0.z;
                 float bv = (j_ == 0) ? nx0.x : (j_ == 1) ? nx0.y : nx0.z;
                 tv = av * bv; }
          S[992 + lane] = tv;
        }
      }
      // prefetch P-row for t+2
      if (t + 2 < cl) {
        int d2 = Si[1008 + t + 2];
        const float4* Pp = (const float4*)(Pg + (size_t)d2 * 816);
        pb0 = Pp[lane]; pb1 = Pp[64 + lane]; pb2 = Pp[128 + lane]; pb3 = Pp[l3];
      }
    }
  }

  // ---------------- epilogue: rank->channel, write out ----------------
  if (lane < 48) S[lane] = accA;
  #pragma unroll
  for (int p = 0; p < 3; p++) S[48 + lane + 64 * p] = acc[p];
  #pragma unroll
  for (int p = 0; p < 9; p++) {
    int u = lane + 64 * p;
    int s = u / 144, m = u - 144 * s, ij = m >> 4, r = m & 15;
    S[240 + s * 180 + ij * 20 + r] = acc[3 + p];
  }

  const size_t baseV = (size_t)N * 128;
  const size_t baseD = (size_t)N * 320;

  // B_a
  #pragma unroll
  for (int h = 0; h < 2; h++) {
    int c = lane + 64 * h;
    float a_ = 0.0f;
    #pragma unroll
    for (int k = 0; k < 3; k++) {
      const float4* w = (const float4*)(Wo_a + k * 2048 + c * 16);
      const float4* A4 = (const float4*)(&S[k * 16]);
      #pragma unroll
      for (int cc = 0; cc < 4; cc++) a_ += dot4(w[cc], A4[cc]);
    }
    out[(size_t)n * 128 + c] = a_;
  }
  // B_v (d = lane)
  {
    float o0 = 0, o1 = 0, o2 = 0;
    #pragma unroll
    for (int k = 0; k < 4; k++) {
      const float4* w = (const float4*)(Wo_v + k * 1024 + lane * 16);
      float4 w0 = w[0], w1 = w[1], w2 = w[2], w3 = w[3];
      #pragma unroll
      for (int j = 0; j < 3; j++) {
        const float4* A4 = (const float4*)(&S[48 + k * 48 + j * 16]);
        float v = dot4(w0, A4[0]) + dot4(w1, A4[1]) + dot4(w2, A4[2]) + dot4(w3, A4[3]);
        if (j == 0) o0 += v; else if (j == 1) o1 += v; else o2 += v;
      }
    }
    size_t ov = baseV + (size_t)n * 192 + lane * 3;
    out[ov] = o0; out[ov + 1] = o1; out[ov + 2] = o2;
  }
  // B_d
  #pragma unroll
  for (int p = 0; p < 5; p++) {
    int t = lane + 64 * p;
    if (t < 288) {
      int d = t / 9, ij = t - 9 * d;
      float a_ = 0.0f;
      #pragma unroll
      for (int s = 0; s < 4; s++) {
        const float4* w = (const float4*)(Wo_d + s * 512 + d * 16);
        const float4* A4 = (const float4*)(&S[240 + s * 180 + ij * 20]);
        a_ += dot4(w[0], A4[0]) + dot4(w[1], A4[1]) + dot4(w[2], A4[2]) + dot4(w[3], A4[3]);
      }
      out[baseD + (size_t)n * 288 + t] = a_;
    }
  }
}

// ---------------------------------------------------------------------------
extern "C" void kernel_launch(void* const* d_in, const int* in_sizes, int n_in,
                              void* d_out, int out_size, void* d_ws, size_t ws_size,
                              hipStream_t stream) {
  const float* r_ij = (const float*)d_in[0];
  const float* x_a  = (const float*)d_in[1];
  const float* x_v  = (const float*)d_in[2];
  const float* x_d  = (const float*)d_in[3];
  const float* W1_a = (const float*)d_in[4];
  const float* W1_v = (const float*)d_in[5];
  const float* W1_d = (const float*)d_in[6];
  const float* W2   = (const float*)d_in[7];
  const float* Wo_a = (const float*)d_in[8];
  const float* Wo_v = (const float*)d_in[9];
  const float* Wo_d = (const float*)d_in[10];
  const int*  src   = (const int*)d_in[11];
  const int*  dst   = (const int*)d_in[12];

  const int E = in_sizes[0] / 3;
  const int N = in_sizes[1] / 128;

  float* P    = (float*)d_ws;
  int* counts = (int*)(P + (size_t)N * 816);
  int* offs   = counts + N;
  int* cursor = offs + N + 1;
  int* eidx   = cursor + N;

  hipMemsetAsync(counts, 0, sizeof(int) * (size_t)N, stream);

  hist_kernel<<<(E + 255) / 256, 256, 0, stream>>>(src, counts, E);
  scan_kernel<<<1, 1024, 0, stream>>>(counts, offs, cursor, N, E);
  scatter_kernel<<<(E + 255) / 256, 256, 0, stream>>>(src, cursor, eidx, E);
  dim3 g1((N + 63) / 64, 4);
  node_proj_kernel<<<g1, 256, 0, stream>>>(x_a, x_v, x_d, W1_a, W1_v, W1_d, P, N);
  node_gather_kernel<<<(N + 3) / 4, 256, 0, stream>>>(r_ij, dst, offs, eidx, P, W2,
                                                      Wo_a, Wo_v, Wo_d, (float*)d_out, N);
}

// Round 8
// 395.003 us; speedup vs baseline: 1.2263x; 1.1562x over previous
//
#include <hip/hip_runtime.h>
#include <hip/hip_bf16.h>
#include <math.h>

#define PI_F 3.14159265358979323846f
#define R0_F 5.0f

// ---------------------------------------------------------------------------
// ws layout:
//   P[n][816] float : per-node input projections, GROUP-MAJOR layout v2:
//     lane-group g owns region gbase[g], value j of group g for rank r sits at
//     gbase[g] + j*16 + r.
//     g0 @0   : j0-8 pd222[ij], j9-11 pv110[i], j12 pa000      (208)
//     g1 @208 : j0-8 pd202[ij], j9-11 pv101[i], j12 pa011      (208)
//     g2 @416 : j0-8 pd211[ij], j9-11 pv121[i], j12 pa022      (208)
//     g3 @624 : j0-8 pd220[ij], j9-11 pv112[i]                 (192)
//   counts[N] | offs[N+1] | cursor[N] | eidx[E]   (ints, CSR by src)
// ---------------------------------------------------------------------------

static __device__ __forceinline__ float dot4(float4 a, float4 b) {
  return a.x * b.x + a.y * b.y + a.z * b.z + a.w * b.w;
}

// ------------------- K1: per-node input projections (v4) --------------------
// blockIdx.y = phase (0:A, 1:V, 2:D1, 3:D2); compute identical to v3, only
// the final P-store index mapping changed to the group-major layout above.
__global__ __launch_bounds__(256) void node_proj_kernel(
    const float* __restrict__ x_a, const float* __restrict__ x_v, const float* __restrict__ x_d,
    const float* __restrict__ W1_a, const float* __restrict__ W1_v, const float* __restrict__ W1_d,
    float* __restrict__ P, int N)
{
  __shared__ float S[12352];           // 48.25 KB
  const int tid = threadIdx.x;
  const int lane = tid & 63;
  const int wu = __builtin_amdgcn_readfirstlane(tid >> 6);  // uniform wave id 0..3
  const int n0 = blockIdx.x * 64;
  const int nrem = min(N - n0, 64);    // valid nodes in this block
  const int phase = blockIdx.y;

  if (phase == 0) {
    // ===== Phase A: xa(128) -> pa000/pa011/pa022 (j12 of g0/g1/g2) =========
    for (int idx4 = tid; idx4 < nrem * 32; idx4 += 256) {
      int n = idx4 >> 5, c4 = idx4 & 31;
      float4 v = ((const float4*)(x_a + (size_t)(n0 + n) * 128))[c4];
      float* d = &S[n * 129 + c4 * 4];
      d[0] = v.x; d[1] = v.y; d[2] = v.z; d[3] = v.w;
    }
    __syncthreads();
    float acc[12];
    #pragma unroll
    for (int q = 0; q < 12; q++) acc[q] = 0.0f;
    const float* xrow = &S[lane * 129];
    for (int c0 = 0; c0 < 128; c0 += 16) {
      float xr[16];
      #pragma unroll
      for (int j = 0; j < 16; j++) xr[j] = xrow[c0 + j];
      #pragma unroll
      for (int q = 0; q < 12; q++) {
        int o = wu * 12 + q;                       // o = k*16+r
        const float* wp = W1_a + (o >> 4) * 2048 + (o & 15) * 128 + c0;
        float s = 0.0f;
        #pragma unroll
        for (int j = 0; j < 16; j++) s += wp[j] * xr[j];
        acc[q] += s;
      }
    }
    __syncthreads();
    #pragma unroll
    for (int q = 0; q < 12; q++) S[lane * 49 + wu * 12 + q] = acc[q];
    __syncthreads();
    // store: pa_k[r] -> gA[k] + 192 + r    (gA = 0,208,416)
    for (int u = tid; u < nrem * 48; u += 256) {
      int n = u / 48, m = u - n * 48, k = m >> 4, r = m & 15;
      int gA = (k == 0) ? 0 : (k == 1) ? 208 : 416;
      P[(size_t)(n0 + n) * 816 + gA + 192 + r] = S[n * 49 + m];
    }
  } else if (phase == 1) {
    // ===== Phase V: xv(64,3) -> pv101/pv110/pv112/pv121 (j9-11) =============
    for (int idx4 = tid; idx4 < nrem * 48; idx4 += 256) {
      int n = idx4 / 48, m4 = idx4 - n * 48;
      float4 v = ((const float4*)(x_v + (size_t)(n0 + n) * 192))[m4];
      float* d = &S[n * 193 + m4 * 4];
      d[0] = v.x; d[1] = v.y; d[2] = v.z; d[3] = v.w;
    }
    __syncthreads();
    float acc[16][3];
    #pragma unroll
    for (int r = 0; r < 16; r++)
      #pragma unroll
      for (int i = 0; i < 3; i++) acc[r][i] = 0.0f;
    const float* xrow = &S[lane * 193];
    for (int c0 = 0; c0 < 64; c0 += 16) {
      float xr[16][3];
      #pragma unroll
      for (int j = 0; j < 16; j++) {
        xr[j][0] = xrow[(c0 + j) * 3 + 0];
        xr[j][1] = xrow[(c0 + j) * 3 + 1];
        xr[j][2] = xrow[(c0 + j) * 3 + 2];
      }
      #pragma unroll
      for (int r = 0; r < 16; r++) {
        const float* wp = W1_v + wu * 1024 + r * 64 + c0;   // k = wu (101,110,112,121)
        #pragma unroll
        for (int j = 0; j < 16; j++) {
          float w = wp[j];
          acc[r][0] += w * xr[j][0];
          acc[r][1] += w * xr[j][1];
          acc[r][2] += w * xr[j][2];
        }
      }
    }
    __syncthreads();
    #pragma unroll
    for (int r = 0; r < 16; r++)
      #pragma unroll
      for (int i = 0; i < 3; i++)
        S[lane * 193 + wu * 48 + r * 3 + i] = acc[r][i];
    __syncthreads();
    // store: path k value i rank r -> gV[k] + (9+i)*16 + r
    // gV: 101->g1(208), 110->g0(0), 112->g3(624), 121->g2(416)
    for (int u = tid; u < nrem * 192; u += 256) {
      int n = u / 192, m = u - n * 192;
      int k = m / 48, mm = m - k * 48, r = mm / 3, i = mm - r * 3;
      int gV = (k == 0) ? 208 : (k == 1) ? 0 : (k == 2) ? 624 : 416;
      P[(size_t)(n0 + n) * 816 + gV + 144 + i * 16 + r] = S[n * 193 + m];
    }
  } else if (phase == 2) {
    // ===== Phase D1: xd(32, ij=0..4) -> pd* j=ij<5 ==========================
    for (int idx = tid; idx < nrem * 160; idx += 256) {
      int n = idx / 160, m = idx - n * 160, c = m / 5, ij = m - c * 5;
      S[n * 161 + m] = x_d[(size_t)(n0 + n) * 288 + c * 9 + ij];
    }
    __syncthreads();
    float acc[16][5];
    #pragma unroll
    for (int r = 0; r < 16; r++)
      #pragma unroll
      for (int t = 0; t < 5; t++) acc[r][t] = 0.0f;
    const float* xrow = &S[lane * 161];
    for (int c0 = 0; c0 < 32; c0 += 8) {
      float xr[8][5];
      #pragma unroll
      for (int j = 0; j < 8; j++)
        #pragma unroll
        for (int t = 0; t < 5; t++) xr[j][t] = xrow[(c0 + j) * 5 + t];
      #pragma unroll
      for (int r = 0; r < 16; r++) {
        const float* wp = W1_d + wu * 512 + r * 32 + c0;    // k = wu (202,211,220,222)
        #pragma unroll
        for (int j = 0; j < 8; j++) {
          float w = wp[j];
          #pragma unroll
          for (int t = 0; t < 5; t++) acc[r][t] += w * xr[j][t];
        }
      }
    }
    #pragma unroll
    for (int h = 0; h < 2; h++) {
      __syncthreads();
      if ((lane >> 5) == h) {
        int l5 = lane & 31;
        #pragma unroll
        for (int r = 0; r < 16; r++)
          #pragma unroll
          for (int t = 0; t < 5; t++)
            S[l5 * 321 + wu * 80 + r * 5 + t] = acc[r][t];
      }
      __syncthreads();
      int nbase = h * 32;
      int cnt = min(nrem - nbase, 32);
      // store: path k comp ij=t rank r -> gD[k] + t*16 + r
      // gD: 202->g1(208), 211->g2(416), 220->g3(624), 222->g0(0)
      for (int u = tid; u < cnt * 320; u += 256) {
        int n = u / 320, m = u - n * 320;
        int k = m / 80, mm = m - k * 80, r = mm / 5, t = mm - r * 5;
        int gD = (k == 0) ? 208 : (k == 1) ? 416 : (k == 2) ? 624 : 0;
        P[(size_t)(n0 + nbase + n) * 816 + gD + t * 16 + r] = S[n * 321 + m];
      }
    }
  } else {
    // ===== Phase D2: xd(32, ij=5..8) -> pd* j=ij>=5 =========================
    for (int idx = tid; idx < nrem * 128; idx += 256) {
      int n = idx >> 7, m = idx & 127, c = m >> 2, t = m & 3;
      S[n * 129 + m] = x_d[(size_t)(n0 + n) * 288 + c * 9 + 5 + t];
    }
    __syncthreads();
    float acc[16][4];
    #pragma unroll
    for (int r = 0; r < 16; r++)
      #pragma unroll
      for (int t = 0; t < 4; t++) acc[r][t] = 0.0f;
    const float* xrow = &S[lane * 129];
    for (int c0 = 0; c0 < 32; c0 += 8) {
      float xr[8][4];
      #pragma unroll
      for (int j = 0; j < 8; j++)
        #pragma unroll
        for (int t = 0; t < 4; t++) xr[j][t] = xrow[(c0 + j) * 4 + t];
      #pragma unroll
      for (int r = 0; r < 16; r++) {
        const float* wp = W1_d + wu * 512 + r * 32 + c0;
        #pragma unroll
        for (int j = 0; j < 8; j++) {
          float w = wp[j];
          #pragma unroll
          for (int t = 0; t < 4; t++) acc[r][t] += w * xr[j][t];
        }
      }
    }
    #pragma unroll
    for (int h = 0; h < 2; h++) {
      __syncthreads();
      if ((lane >> 5) == h) {
        int l5 = lane & 31;
        #pragma unroll
        for (int r = 0; r < 16; r++)
          #pragma unroll
          for (int t = 0; t < 4; t++)
            S[l5 * 257 + wu * 64 + r * 4 + t] = acc[r][t];
      }
      __syncthreads();
      int nbase = h * 32;
      int cnt = min(nrem - nbase, 32);
      for (int u = tid; u < cnt * 256; u += 256) {
        int n = u >> 8, m = u & 255;
        int k = m >> 6, mm = m & 63, r = mm >> 2, t = mm & 3;
        int gD = (k == 0) ? 208 : (k == 1) ? 416 : (k == 2) ? 624 : 0;
        P[(size_t)(n0 + nbase + n) * 816 + gD + (5 + t) * 16 + r] = S[n * 257 + m];
      }
    }
  }
}

// ------------------- CSR build ---------------------------------------------
__global__ void hist_kernel(const int* __restrict__ src, int* __restrict__ counts, int E) {
  int e = blockIdx.x * 256 + threadIdx.x;
  if (e < E) atomicAdd(&counts[src[e]], 1);
}

__global__ __launch_bounds__(1024) void scan_kernel(
    const int* __restrict__ counts, int* __restrict__ offs, int* __restrict__ cursor,
    int N, int E)
{
  __shared__ int part[1024];
  int tid = threadIdx.x;
  int chunk = (N + 1023) / 1024;
  int lo = tid * chunk, hi = min(lo + chunk, N);
  int s = 0;
  for (int i = lo; i < hi; i++) s += counts[i];
  part[tid] = s;
  __syncthreads();
  for (int off = 1; off < 1024; off <<= 1) {
    int v = (tid >= off) ? part[tid - off] : 0;
    __syncthreads();
    part[tid] += v;
    __syncthreads();
  }
  int run = part[tid] - s;
  for (int i = lo; i < hi; i++) { offs[i] = run; cursor[i] = run; run += counts[i]; }
  if (tid == 0) offs[N] = E;
}

__global__ void scatter_kernel(const int* __restrict__ src, int* __restrict__ cursor,
                               int* __restrict__ eidx, int E) {
  int e = blockIdx.x * 256 + threadIdx.x;
  if (e < E) { int p = atomicAdd(&cursor[src[e]], 1); eidx[p] = e; }
}

// ------------------- K2 v8: lane-private P partition, ~3 DS ops/edge --------
// 4 independent waves/block (one node each), barrier-free. lane = g*16 + r:
// group g owns paths g0={222,110,000} g1={202,101,011} g2={211,121,022}
// g3={220,112} -> 13 lane-private P values loaded DIRECTLY global->VGPR
// (13 x global_load_dword off one base, coalesced over the 16 r-lanes),
// double-buffered 2 edges ahead (PA/PB, static indices only). q's computed
// in-register from hoisted W2 rows. Per-edge LDS: 3 broadcast b128 reads of
// the compacted rv/rad table (v7's ~105 scalar DS ops/edge eliminated).
// No inline asm, no launch_bounds min-waves (rounds-2/3 scratch cliff).
// Per-wave LDS floats (1792): [0,960) epilogue ACC | [960,1728) scal
// (64 x 3 float4: rv,rad03,rad47) | [1728,1792) dstl (ints).
#define EDGE_BODY(T, PC)                                                       \
  {                                                                            \
    const int t_ = (T);                                                        \
    float4 rvv = S4[240 + 3 * t_];                                             \
    float4 ra_ = S4[240 + 3 * t_ + 1];                                         \
    float4 rb_ = S4[240 + 3 * t_ + 2];                                         \
    float q0 = dot4(w0a, ra_) + dot4(w0b, rb_);                                \
    float q1 = dot4(w1a, ra_) + dot4(w1b, rb_);                                \
    float q2 = dot4(w2a, ra_) + dot4(w2b, rb_);                                \
    float rv0 = rvv.x, rv1 = rvv.y, rv2 = rvv.z;                               \
    if (g == 0) {                                                              \
      float t0 = PC[0] * rv0 + PC[1] * rv1 + PC[2] * rv2;                      \
      float t1 = PC[3] * rv0 + PC[4] * rv1 + PC[5] * rv2;                      \
      float t2 = PC[6] * rv0 + PC[7] * rv1 + PC[8] * rv2;                      \
      float u0 = q0 * t0, u1 = q0 * t1, u2 = q0 * t2;                          \
      accD[0] += u0 * rv0; accD[1] += u0 * rv1; accD[2] += u0 * rv2;           \
      accD[3] += u1 * rv0; accD[4] += u1 * rv1; accD[5] += u1 * rv2;           \
      accD[6] += u2 * rv0; accD[7] += u2 * rv1; accD[8] += u2 * rv2;           \
      accS += q1 * (PC[9] * rv0 + PC[10] * rv1 + PC[11] * rv2);                \
      accT += q2 * PC[12];                                                     \
    } else if (g == 1) {                                                       \
      _Pragma("unroll")                                                        \
      for (int j = 0; j < 9; j++) accD[j] += q0 * PC[j];                       \
      accV[0] += q1 * PC[9]; accV[1] += q1 * PC[10]; accV[2] += q1 * PC[11];   \
      float o = q2 * PC[12];                                                   \
      accW[0] += o * rv0; accW[1] += o * rv1; accW[2] += o * rv2;              \
    } else if (g == 2) {                                                       \
      accV[0] += q0 * (PC[0] * rv0 + PC[1] * rv1 + PC[2] * rv2);               \
      accV[1] += q0 * (PC[3] * rv0 + PC[4] * rv1 + PC[5] * rv2);               \
      accV[2] += q0 * (PC[6] * rv0 + PC[7] * rv1 + PC[8] * rv2);               \
      float s_ = q1 * (PC[9] * rv0 + PC[10] * rv1 + PC[11] * rv2);             \
      accW[0] += s_ * rv0; accW[1] += s_ * rv1; accW[2] += s_ * rv2;           \
      float o = q2 * PC[12];                                                   \
      float o0 = o * rv0, o1 = o * rv1, o2 = o * rv2;                          \
      accD[0] += o0 * rv0; accD[1] += o0 * rv1; accD[2] += o0 * rv2;           \
      accD[3] += o1 * rv0; accD[4] += o1 * rv1; accD[5] += o1 * rv2;           \
      accD[6] += o2 * rv0; accD[7] += o2 * rv1; accD[8] += o2 * rv2;           \
    } else {                                                                   \
      float t0 = PC[0] * rv0 + PC[1] * rv1 + PC[2] * rv2;                      \
      float t1 = PC[3] * rv0 + PC[4] * rv1 + PC[5] * rv2;                      \
      float t2 = PC[6] * rv0 + PC[7] * rv1 + PC[8] * rv2;                      \
      accS += q0 * (t0 * rv0 + t1 * rv1 + t2 * rv2);                           \
      float m0 = q1 * PC[9], m1 = q1 * PC[10], m2 = q1 * PC[11];               \
      accD[0] += m0 * rv0; accD[1] += m0 * rv1; accD[2] += m0 * rv2;           \
      accD[3] += m1 * rv0; accD[4] += m1 * rv1; accD[5] += m1 * rv2;           \
      accD[6] += m2 * rv0; accD[7] += m2 * rv1; accD[8] += m2 * rv2;           \
    }                                                                          \
    if (t_ + 2 < cl) {                                                         \
      const float* bp = PbaseG + (size_t)Si[1728 + t_ + 2] * 816;              \
      _Pragma("unroll")                                                        \
      for (int j = 0; j < 13; j++) PC[j] = bp[j * 16];                         \
    }                                                                          \
  }

__global__ __launch_bounds__(256) void node_gather_kernel(
    const float* __restrict__ r_ij, const int* __restrict__ dst,
    const int* __restrict__ offs, const int* __restrict__ eidx,
    const float* __restrict__ Pg, const float* __restrict__ W2,
    const float* __restrict__ Wo_a, const float* __restrict__ Wo_v, const float* __restrict__ Wo_d,
    float* __restrict__ out, int N)
{
  __shared__ __align__(16) float Sall[7168];    // 4 x 1792 = 28.7 KB
  const int wid = threadIdx.x >> 6;
  const int lane = threadIdx.x & 63;
  const int n = blockIdx.x * 4 + wid;
  if (n >= N) return;
  float* S = Sall + wid * 1792;
  float4* S4 = (float4*)S;
  int* Si = (int*)S;
  const int off = offs[n], deg = offs[n + 1] - off;
  const int g = lane >> 4, r = lane & 15;
  const int gbase = (g == 0) ? 0 : (g == 1) ? 208 : (g == 2) ? 416 : 624;
  const float* PbaseG = Pg + gbase + r;

  // ---- hoist this lane's 3 W2 rows (path q's; g3 duplicates row 8) ----
  int i0, i1, i2;
  if (g == 0)      { i0 = 10; i1 = 1; i2 = 0; }   // 222,110,000
  else if (g == 1) { i0 = 9;  i1 = 4; i2 = 3; }   // 202,101,011
  else if (g == 2) { i0 = 6;  i1 = 5; i2 = 7; }   // 211,121,022
  else             { i0 = 2;  i1 = 8; i2 = 8; }   // 220,112,(unused)
  const float4* w2p0 = (const float4*)(W2 + (i0 * 16 + r) * 8);
  const float4* w2p1 = (const float4*)(W2 + (i1 * 16 + r) * 8);
  const float4* w2p2 = (const float4*)(W2 + (i2 * 16 + r) * 8);
  float4 w0a = w2p0[0], w0b = w2p0[1];
  float4 w1a = w2p1[0], w1b = w2p1[1];
  float4 w2a = w2p2[0], w2b = w2p2[1];

  float accD[9], accV[3], accW[3], accS = 0.0f, accT = 0.0f;
  #pragma unroll
  for (int j = 0; j < 9; j++) accD[j] = 0.0f;
  #pragma unroll
  for (int j = 0; j < 3; j++) { accV[j] = 0.0f; accW[j] = 0.0f; }

  float PA[13], PB[13];

  for (int base = 0; base < deg; base += 64) {
    const int cnt = min(deg - base, 64);
    // ---- chunk prologue: lane = edge; compute + ballot-compact live edges --
    bool live = false;
    float a = 0, b = 0, c = 0;
    int d = 0;
    if (lane < cnt) {
      int e = eidx[off + base + lane];
      a = r_ij[3 * (size_t)e]; b = r_ij[3 * (size_t)e + 1]; c = r_ij[3 * (size_t)e + 2];
      d = dst[e];
      live = (a * a + b * b + c * c) < 5.0f;
    }
    unsigned long long mb = __ballot(live);
    const int cl = __popcll(mb);
    if (live) {
      int pos = __popcll(mb & ((1ull << lane) - 1ull));
      float rr = a * a + b * b + c * c;
      float x_sq = rr * (1.0f / R0_F);
      float env = 1.0f - x_sq;
      float v0 = a * (17.0f / R0_F), v1 = b * (17.0f / R0_F), v2 = c * (17.0f / R0_F);
      float nn = sqrtf(v0 * v0 + v1 * v1 + v2 * v2);
      float sig = 2.0f / (1.0f + __expf(-nn)) - 1.0f;
      float scs = sig / (nn + 1e-6f);
      float rv0 = v0 * scs, rv1 = v1 * scs, rv2 = v2 * scs;
      float c1 = __cosf(PI_F * sqrtf(x_sq));
      float two_c1 = 2.0f * c1, cm2 = 1.0f, cm1 = c1;
      float rad[8];
      rad[0] = env; rad[1] = c1 * env;
      #pragma unroll
      for (int k = 2; k < 8; k++) { float cc = two_c1 * cm1 - cm2; rad[k] = cc * env; cm2 = cm1; cm1 = cc; }
      Si[1728 + pos] = d;
      S4[240 + 3 * pos]     = make_float4(rv0, rv1, rv2, 0.0f);
      S4[240 + 3 * pos + 1] = make_float4(rad[0], rad[1], rad[2], rad[3]);
      S4[240 + 3 * pos + 2] = make_float4(rad[4], rad[5], rad[6], rad[7]);
    }
    if (cl == 0) continue;
    // ---- warm-up: load P for edges 0 and 1 ----
    {
      const float* bp = PbaseG + (size_t)Si[1728] * 816;
      #pragma unroll
      for (int j = 0; j < 13; j++) PA[j] = bp[j * 16];
      if (cl > 1) {
        const float* bq = PbaseG + (size_t)Si[1729] * 816;
        #pragma unroll
        for (int j = 0; j < 13; j++) PB[j] = bq[j * 16];
      }
    }
    // ---- main loop: 2x unrolled so PA/PB roles are compile-time ----
    for (int t = 0; t < cl; t += 2) {
      EDGE_BODY(t, PA)
      if (t + 1 < cl) {
        EDGE_BODY(t + 1, PB)
      }
    }
  }

  // ---------------- epilogue: write accs into classic ACC layout ------------
  // A: S[k*16+r] k:000,110,220 | V: S[48+kv*48+j*16+r] kv:011,101,121,211
  // D: S[240+s*180+ij*20+r]    s:022,112,202,222
  if (g == 0) {
    S[r] = accT;                                     // 000
    S[16 + r] = accS;                                // 110
    #pragma unroll
    for (int ij = 0; ij < 9; ij++) S[240 + 540 + ij * 20 + r] = accD[ij];   // 222
  } else if (g == 1) {
    #pragma unroll
    for (int j = 0; j < 3; j++) {
      S[48 + j * 16 + r] = accW[j];                  // 011
      S[96 + j * 16 + r] = accV[j];                  // 101
    }
    #pragma unroll
    for (int ij = 0; ij < 9; ij++) S[240 + 360 + ij * 20 + r] = accD[ij];   // 202
  } else if (g == 2) {
    #pragma unroll
    for (int j = 0; j < 3; j++) {
      S[144 + j * 16 + r] = accW[j];                 // 121
      S[192 + j * 16 + r] = accV[j];                 // 211
    }
    #pragma unroll
    for (int ij = 0; ij < 9; ij++) S[240 + ij * 20 + r] = accD[ij];         // 022
  } else {
    S[32 + r] = accS;                                // 220
    #pragma unroll
    for (int ij = 0; ij < 9; ij++) S[240 + 180 + ij * 20 + r] = accD[ij];   // 112
  }

  const size_t baseV = (size_t)N * 128;
  const size_t baseD = (size_t)N * 320;

  // B_a
  #pragma unroll
  for (int h = 0; h < 2; h++) {
    int c = lane + 64 * h;
    float a_ = 0.0f;
    #pragma unroll
    for (int k = 0; k < 3; k++) {
      const float4* w = (const float4*)(Wo_a + k * 2048 + c * 16);
      const float4* A4 = (const float4*)(&S[k * 16]);
      #pragma unroll
      for (int cc = 0; cc < 4; cc++) a_ += dot4(w[cc], A4[cc]);
    }
    out[(size_t)n * 128 + c] = a_;
  }
  // B_v (d = lane)
  {
    float o0 = 0, o1 = 0, o2 = 0;
    #pragma unroll
    for (int k = 0; k < 4; k++) {
      const float4* w = (const float4*)(Wo_v + k * 1024 + lane * 16);
      float4 w0 = w[0], w1 = w[1], w2 = w[2], w3 = w[3];
      #pragma unroll
      for (int j = 0; j < 3; j++) {
        const float4* A4 = (const float4*)(&S[48 + k * 48 + j * 16]);
        float v = dot4(w0, A4[0]) + dot4(w1, A4[1]) + dot4(w2, A4[2]) + dot4(w3, A4[3]);
        if (j == 0) o0 += v; else if (j == 1) o1 += v; else o2 += v;
      }
    }
    size_t ov = baseV + (size_t)n * 192 + lane * 3;
    out[ov] = o0; out[ov + 1] = o1; out[ov + 2] = o2;
  }
  // B_d
  #pragma unroll
  for (int p = 0; p < 5; p++) {
    int t = lane + 64 * p;
    if (t < 288) {
      int d = t / 9, ij = t - 9 * d;
      float a_ = 0.0f;
      #pragma unroll
      for (int s = 0; s < 4; s++) {
        const float4* w = (const float4*)(Wo_d + s * 512 + d * 16);
        const float4* A4 = (const float4*)(&S[240 + s * 180 + ij * 20]);
        a_ += dot4(w[0], A4[0]) + dot4(w[1], A4[1]) + dot4(w[2], A4[2]) + dot4(w[3], A4[3]);
      }
      out[baseD + (size_t)n * 288 + t] = a_;
    }
  }
}

// ---------------------------------------------------------------------------
extern "C" void kernel_launch(void* const* d_in, const int* in_sizes, int n_in,
                              void* d_out, int out_size, void* d_ws, size_t ws_size,
                              hipStream_t stream) {
  const float* r_ij = (const float*)d_in[0];
  const float* x_a  = (const float*)d_in[1];
  const float* x_v  = (const float*)d_in[2];
  const float* x_d  = (const float*)d_in[3];
  const float* W1_a = (const float*)d_in[4];
  const float* W1_v = (const float*)d_in[5];
  const float* W1_d = (const float*)d_in[6];
  const float* W2   = (const float*)d_in[7];
  const float* Wo_a = (const float*)d_in[8];
  const float* Wo_v = (const float*)d_in[9];
  const float* Wo_d = (const float*)d_in[10];
  const int*  src   = (const int*)d_in[11];
  const int*  dst   = (const int*)d_in[12];

  const int E = in_sizes[0] / 3;
  const int N = in_sizes[1] / 128;

  float* P    = (float*)d_ws;
  int* counts = (int*)(P + (size_t)N * 816);
  int* offs   = counts + N;
  int* cursor = offs + N + 1;
  int* eidx   = cursor + N;

  hipMemsetAsync(counts, 0, sizeof(int) * (size_t)N, stream);

  hist_kernel<<<(E + 255) / 256, 256, 0, stream>>>(src, counts, E);
  scan_kernel<<<1, 1024, 0, stream>>>(counts, offs, cursor, N, E);
  scatter_kernel<<<(E + 255) / 256, 256, 0, stream>>>(src, cursor, eidx, E);
  dim3 g1((N + 63) / 64, 4);
  node_proj_kernel<<<g1, 256, 0, stream>>>(x_a, x_v, x_d, W1_a, W1_v, W1_d, P, N);
  node_gather_kernel<<<(N + 3) / 4, 256, 0, stream>>>(r_ij, dst, offs, eidx, P, W2,
                                                      Wo_a, Wo_v, Wo_d, (float*)d_out, N);
}